// Round 12
// baseline (143146.350 us; speedup 1.0000x reference)
//
#include <hip/hip_runtime.h>
#include <cmath>

#define NBLK 256
#define NTHR 1024
#define Bv 64
#define Lv 4
#define Hv 512
#define Tv 256
#define G4 2048

// ws layout (bytes)
#define WT_OFF   0u                       // [256 blk][4 l][8 col][1024 k] f32 = 32 MB
#define HT_OFF   (33554432u)              // hT [2 par][4 l][128 k4][64 b][4] f32 = 1 MB
#define YT_OFF   (HT_OFF + 1048576u)      // yT [128][64][4] f32 = 128 KB
#define BIAS_OFF (YT_OFF + 131072u)       // biasC [4][2048] f32 = 32 KB
#define BAR_OFF  (BIAS_OFF + 32768u)      // bar8: 8 counters @ 64B stride

__device__ __forceinline__ float sigmoidf_(float x) {
    return 1.0f / (1.0f + __expf(-x));
}
__device__ __forceinline__ float lo32f(unsigned long long v) {
    return __uint_as_float((unsigned)(v & 0xffffffffu));
}
__device__ __forceinline__ float hi32f(unsigned long long v) {
    return __uint_as_float((unsigned)(v >> 32));
}

// wt[bid][l][col][k]: col = 4*(hn&1)+g for hn = bid*2 + (col>>2);
// k<512 from Wih[l][g*512+hn][k], k>=512 from Whh[l][g*512+hn][k-512]
__global__ __launch_bounds__(256) void prep_wt(const float* __restrict__ Wih,
                                               const float* __restrict__ Whh,
                                               float* __restrict__ wt) {
    int bid = blockIdx.x, tid = threadIdx.x;
    float* dst = wt + (size_t)bid * (4 * 8 * 1024);
    int k = tid * 4;
#pragma unroll
    for (int l = 0; l < 4; ++l)
#pragma unroll
        for (int col = 0; col < 8; ++col) {
            int hn = bid * 2 + (col >> 2);
            int g  = col & 3;
            const float* src = (k < 512)
                ? (Wih + ((size_t)l * G4 + g * Hv + hn) * Hv + k)
                : (Whh + ((size_t)l * G4 + g * Hv + hn) * Hv + (k - 512));
            *(float4*)(dst + (size_t)(l * 8 + col) * 1024 + k) = *(const float4*)src;
        }
}

// biasC[l][4*hn+g] = bih[l][g*512+hn] + bhh[l][g*512+hn]
__global__ void prep_bias(const float* __restrict__ bih, const float* __restrict__ bhh,
                          float* __restrict__ biasC) {
    int idx = blockIdx.x * 256 + threadIdx.x;       // 8192
    int l = idx >> 11, gi = idx & 2047;
    int hn = gi >> 2, g = gi & 3;
    biasC[idx] = bih[l * G4 + g * Hv + hn] + bhh[l * G4 + g * Hv + hn];
}

// yT[k4][b][sub] = y[b][4*k4+sub]; hT[1][l][k4][b][sub] = h0[l][b][4*k4+sub]
__global__ void prep_act(const float* __restrict__ y, const float* __restrict__ h0,
                         float* __restrict__ yT, float* __restrict__ hT) {
    int idx = blockIdx.x * 256 + threadIdx.x;
    if (idx < 32768) {
        int k4 = idx >> 8, b = (idx >> 2) & 63, sub = idx & 3;
        yT[idx] = y[b * Hv + k4 * 4 + sub];
    } else if (idx < 32768 + 131072) {
        int r2 = idx - 32768;
        int l = r2 >> 15, r = r2 & 32767;
        int k4 = r >> 8, b = (r >> 2) & 63, sub = r & 3;
        hT[(size_t)(4 + l) * 32768 + r] = h0[((size_t)l * Bv + b) * Hv + k4 * 4 + sub];
    }
}

// Persistent kernel — R11 with the dot loop rebuilt as a sched_barrier-pinned
// 1-chunk-ahead pipeline: per 4-k chunk, {issue next 16B of acts} | pin |
// {8 ds_read_b128 + 32 FMA} | pin. Live act state = 2 chunks (4 u64) by
// construction -> no register blowup, no scratch, regardless of scheduler
// clause-clustering heuristics.
__global__ __launch_bounds__(NTHR) void lstm_persist(
    const float* __restrict__ wt, const float* __restrict__ biasC,
    const float* __restrict__ yT, const float* __restrict__ c0,
    float* __restrict__ hT, float* __restrict__ out,
    int* __restrict__ bar8)
{
    const int bid = blockIdx.x;
    const int tid = threadIdx.x;
    const int b   = tid & 63;
    const int s   = __builtin_amdgcn_readfirstlane(tid >> 6);   // 0..15 wave-uniform

    __shared__ float  wlds[4 * 8 * 1024];   // 128 KB: [l][col][k]
    __shared__ float4 red[16][64];          // 16 KB reduce buffer (two passes)
    __shared__ float  cst[4][2][64];        // 2 KB c-state [l][hn][b]

    // ---- prologue: W slice -> LDS (the only global W read of the kernel) ----
    {
        const float4* src = (const float4*)(wt + (size_t)bid * 32768);
        float4* dst = (float4*)wlds;
#pragma unroll
        for (int i = 0; i < 8; ++i)
            dst[tid + i * NTHR] = src[tid + i * NTHR];
    }
    if (tid < 512) {
        int l = tid >> 7, hn = (tid >> 6) & 1, bb = tid & 63;
        cst[l][hn][bb] = c0[((size_t)l * Bv + bb) * Hv + bid * 2 + hn];
    }
    __syncthreads();

    for (int p = 0; p < Tv * Lv; ++p) {
        const int t = p >> 2, l = p & 3;
        const int par = t & 1, ppar = par ^ 1;

        const float* xa = (l == 0)
            ? (t == 0 ? yT : hT + (size_t)(ppar * 4 + 3) * 32768)
            : hT + (size_t)(par * 4 + (l - 1)) * 32768;
        const float* ha = hT + (size_t)(ppar * 4 + l) * 32768;

        const float* act = (s < 8) ? xa : ha;
        // chunk j covers k = (s&7)*64 + 4j .. +3  ->  u64 idx j*128 + b*2 off base
        const unsigned long long* aq =
            (const unsigned long long*)act + (size_t)(s & 7) * 2048 + b * 2;

        const float* wl = wlds + l * 8192 + s * 64;   // wp[col*1024 + k], k=0..63

        float acc[8];
#pragma unroll
        for (int c = 0; c < 8; ++c) acc[c] = 0.f;

        unsigned long long cl, ch, nl, nh;
        cl = __hip_atomic_load(aq,     __ATOMIC_RELAXED, __HIP_MEMORY_SCOPE_AGENT);
        ch = __hip_atomic_load(aq + 1, __ATOMIC_RELAXED, __HIP_MEMORY_SCOPE_AGENT);
#pragma unroll
        for (int j = 0; j < 16; ++j) {
            if (j < 15) {
                nl = __hip_atomic_load(aq + (size_t)(j + 1) * 128,
                                       __ATOMIC_RELAXED, __HIP_MEMORY_SCOPE_AGENT);
                nh = __hip_atomic_load(aq + (size_t)(j + 1) * 128 + 1,
                                       __ATOMIC_RELAXED, __HIP_MEMORY_SCOPE_AGENT);
            }
            __builtin_amdgcn_sched_barrier(0);   // pin: no load hoisting past here
            {
                float a0 = lo32f(cl), a1 = hi32f(cl);
                float a2 = lo32f(ch), a3 = hi32f(ch);
#pragma unroll
                for (int c = 0; c < 8; ++c) {
                    float4 w4 = *(const float4*)(wl + c * 1024 + j * 4);
                    acc[c] = fmaf(a0, w4.x, acc[c]);
                    acc[c] = fmaf(a1, w4.y, acc[c]);
                    acc[c] = fmaf(a2, w4.z, acc[c]);
                    acc[c] = fmaf(a3, w4.w, acc[c]);
                }
            }
            cl = nl; ch = nh;
            __builtin_amdgcn_sched_barrier(0);   // pin: chunk j+2 loads stay below
        }

        // ---- two-pass gate reduce + epilogue (hn = 0, then hn = 1) ----
#pragma unroll
        for (int hn = 0; hn < 2; ++hn) {
            red[s][b] = make_float4(acc[4 * hn + 0], acc[4 * hn + 1],
                                    acc[4 * hn + 2], acc[4 * hn + 3]);
            __syncthreads();
            if (tid < 64) {
                float gx = 0.f, gy = 0.f, gz = 0.f, gw = 0.f;
#pragma unroll
                for (int ss = 0; ss < 16; ++ss) {
                    float4 r = red[ss][tid];
                    gx += r.x; gy += r.y; gz += r.z; gw += r.w;
                }
                float4 bb4 = *(const float4*)(biasC + l * G4 + bid * 8 + hn * 4);
                float ig = sigmoidf_(gx + bb4.x);
                float fg = sigmoidf_(gy + bb4.y);
                float gv = tanhf(gz + bb4.z);
                float og = sigmoidf_(gw + bb4.w);

                float cn = fg * cst[l][hn][tid] + ig * gv;
                cst[l][hn][tid] = cn;
                float hv = og * tanhf(cn);

                int n = bid * 2 + hn;
                __hip_atomic_store(
                    &hT[(size_t)(par * 4 + l) * 32768 + ((n >> 2) * 64 + tid) * 4 + (n & 3)],
                    hv, __ATOMIC_RELAXED, __HIP_MEMORY_SCOPE_AGENT);
                if (l == Lv - 1)
                    out[((size_t)tid * Tv + t) * Hv + n] = hv;
            }
            __syncthreads();
        }

        // ---- inter-block barrier (monotonic, spread counters, no invalidates)
        if (tid == 0)
            __hip_atomic_fetch_add(&bar8[(bid & 7) * 16], 1,
                                   __ATOMIC_RELEASE, __HIP_MEMORY_SCOPE_AGENT);
        if (tid < 8) {
            const int target = 32 * (p + 1);
            while (__hip_atomic_load(&bar8[tid * 16], __ATOMIC_RELAXED,
                                     __HIP_MEMORY_SCOPE_AGENT) < target) {
                __builtin_amdgcn_s_sleep(1);
            }
        }
        __syncthreads();
    }
}

extern "C" void kernel_launch(void* const* d_in, const int* in_sizes, int n_in,
                              void* d_out, int out_size, void* d_ws, size_t ws_size,
                              hipStream_t stream)
{
    const float* y   = (const float*)d_in[0];
    const float* h0  = (const float*)d_in[1];
    const float* c0  = (const float*)d_in[2];
    const float* Wih = (const float*)d_in[3];
    const float* Whh = (const float*)d_in[4];
    const float* bih = (const float*)d_in[5];
    const float* bhh = (const float*)d_in[6];
    float* out = (float*)d_out;

    char* ws = (char*)d_ws;
    float* wt    = (float*)(ws + WT_OFF);
    float* hT    = (float*)(ws + HT_OFF);
    float* yT    = (float*)(ws + YT_OFF);
    float* biasC = (float*)(ws + BIAS_OFF);
    int*   bar8  = (int*)(ws + BAR_OFF);

    hipMemsetAsync(ws + BAR_OFF, 0, 1024, stream);

    prep_wt<<<NBLK, 256, 0, stream>>>(Wih, Whh, wt);
    prep_bias<<<32, 256, 0, stream>>>(bih, bhh, biasC);
    prep_act<<<(32768 + 131072) / 256, 256, 0, stream>>>(y, h0, yT, hT);

    lstm_persist<<<NBLK, NTHR, 0, stream>>>(wt, biasC, yT, c0, hT, out, bar8);
}

// Round 13
// 20627.449 us; speedup vs baseline: 6.9396x; 6.9396x over previous
//
#include <hip/hip_runtime.h>
#include <cmath>

#define NBLK 256
#define NTHR 1024
#define Bv 64
#define Lv 4
#define Hv 512
#define Tv 256
#define G4 2048

// ws layout (bytes)
#define WT_OFF   0u                       // [256 blk][4 l][8 col][1024 k] f32 = 32 MB
#define HT_OFF   (33554432u)              // hT [2 par][4 l][128 k4][64 b][4] f32 = 1 MB
#define YT_OFF   (HT_OFF + 1048576u)      // yT [128][64][4] f32 = 128 KB
#define BIAS_OFF (YT_OFF + 131072u)       // biasC [4][2048] f32 = 32 KB
#define BAR_OFF  (BIAS_OFF + 32768u)      // bar8: 8 counters @ 64B stride

__device__ __forceinline__ float sigmoidf_(float x) {
    return 1.0f / (1.0f + __expf(-x));
}

// async 16B global -> LDS (dest = wave-uniform base + lane*16)
__device__ __forceinline__ void gload_lds16(const float* g, float* l) {
    __builtin_amdgcn_global_load_lds(
        (const __attribute__((address_space(1))) void*)g,
        (__attribute__((address_space(3))) void*)l, 16, 0, 0);
}

// wt[bid][l][col][k]: col = 4*(hn&1)+g for hn = bid*2 + (col>>2);
// k<512 from Wih[l][g*512+hn][k], k>=512 from Whh[l][g*512+hn][k-512]
__global__ __launch_bounds__(256) void prep_wt(const float* __restrict__ Wih,
                                               const float* __restrict__ Whh,
                                               float* __restrict__ wt) {
    int bid = blockIdx.x, tid = threadIdx.x;
    float* dst = wt + (size_t)bid * (4 * 8 * 1024);
    int k = tid * 4;
#pragma unroll
    for (int l = 0; l < 4; ++l)
#pragma unroll
        for (int col = 0; col < 8; ++col) {
            int hn = bid * 2 + (col >> 2);
            int g  = col & 3;
            const float* src = (k < 512)
                ? (Wih + ((size_t)l * G4 + g * Hv + hn) * Hv + k)
                : (Whh + ((size_t)l * G4 + g * Hv + hn) * Hv + (k - 512));
            *(float4*)(dst + (size_t)(l * 8 + col) * 1024 + k) = *(const float4*)src;
        }
}

// biasC[l][4*hn+g] = bih[l][g*512+hn] + bhh[l][g*512+hn]
__global__ void prep_bias(const float* __restrict__ bih, const float* __restrict__ bhh,
                          float* __restrict__ biasC) {
    int idx = blockIdx.x * 256 + threadIdx.x;       // 8192
    int l = idx >> 11, gi = idx & 2047;
    int hn = gi >> 2, g = gi & 3;
    biasC[idx] = bih[l * G4 + g * Hv + hn] + bhh[l * G4 + g * Hv + hn];
}

// yT[k4][b][sub] = y[b][4*k4+sub]; hT[1][l][k4][b][sub] = h0[l][b][4*k4+sub]
__global__ void prep_act(const float* __restrict__ y, const float* __restrict__ h0,
                         float* __restrict__ yT, float* __restrict__ hT) {
    int idx = blockIdx.x * 256 + threadIdx.x;
    if (idx < 32768) {
        int k4 = idx >> 8, b = (idx >> 2) & 63, sub = idx & 3;
        yT[idx] = y[b * Hv + k4 * 4 + sub];
    } else if (idx < 32768 + 131072) {
        int r2 = idx - 32768;
        int l = r2 >> 15, r = r2 & 32767;
        int k4 = r >> 8, b = (r >> 2) & 63, sub = r & 3;
        hT[(size_t)(4 + l) * 32768 + r] = h0[((size_t)l * Bv + b) * Hv + k4 * 4 + sub];
    }
}

// Persistent kernel — R5 structure with the W path changed from per-phase
// scalar global reads to DOUBLE-BUFFERED per-phase LDS staging:
// during phase p, all waves issue global_load_lds for phase p+1's 32 KB W
// slice (2 x 16B per thread, vector pipe, a full phase of latency budget);
// the dot reads W from the staged buffer via wave-uniform broadcast b128.
// Act loads / epilogue / barrier are R5-verbatim (proven 25ms structure).
__global__ __launch_bounds__(NTHR) void lstm_persist(
    const float* __restrict__ wt, const float* __restrict__ biasC,
    const float* __restrict__ yT, const float* __restrict__ c0,
    float* __restrict__ hT, float* __restrict__ out,
    int* __restrict__ bar8)
{
    const int bid  = blockIdx.x;
    const int tid  = threadIdx.x;
    const int b    = tid & 63;
    const int lane = tid & 63;
    const int wv   = tid >> 6;                                  // wave id 0..15
    const int s    = __builtin_amdgcn_readfirstlane(tid >> 6);  // wave-uniform

    __shared__ float  wstg[2][8192];   // 64 KB: double-buffered W slice [col][k]
    __shared__ float4 redA[16][64];    // cols 0..3 (hn=0)
    __shared__ float4 redB[16][64];    // cols 4..7 (hn=1)
    __shared__ float  cst[4][2][64];   // c state [l][hn][b]

    const float* wtB = wt + (size_t)bid * 32768;

    // stage W slice for layer ls into buffer bn (async; drained by syncthreads)
    #define STAGE(ls, bn) {                                              \
        const float* g_ = wtB + (ls) * 8192 + wv * 512 + lane * 4;       \
        gload_lds16(g_,       &wstg[bn][wv * 512]);                      \
        gload_lds16(g_ + 256, &wstg[bn][wv * 512 + 256]);                \
    }

    if (tid < 512) {
        int l = tid >> 7, hn = (tid >> 6) & 1, bb = tid & 63;
        cst[l][hn][bb] = c0[((size_t)l * Bv + bb) * Hv + bid * 2 + hn];
    }
    STAGE(0, 0);            // phase 0 (l=0) W slice
    __syncthreads();        // drains global_load_lds (vmcnt) + cst writes

    for (int p = 0; p < Tv * Lv; ++p) {
        const int t = p >> 2, l = p & 3;
        const int par = t & 1, ppar = par ^ 1;
        const int cur = p & 1;

        // issue next phase's W staging into the other buffer (fully async)
        if (p + 1 < Tv * Lv) STAGE((p + 1) & 3, cur ^ 1);

        const float* xa = (l == 0)
            ? (t == 0 ? yT : hT + (size_t)(ppar * 4 + 3) * 32768)
            : hT + (size_t)(par * 4 + (l - 1)) * 32768;
        const float* ha = hT + (size_t)(ppar * 4 + l) * 32768;

        // 64 activation floats for batch b, k-slice s*64.. (R5-verbatim loads)
        const float* act = (s < 8) ? xa : ha;
        const unsigned long long* aq =
            (const unsigned long long*)act + (size_t)(s & 7) * 2048 + b * 2;

        float av[64];
#pragma unroll
        for (int j = 0; j < 16; ++j) {
            unsigned long long lo = __hip_atomic_load(aq + (size_t)j * 128,
                                      __ATOMIC_RELAXED, __HIP_MEMORY_SCOPE_AGENT);
            unsigned long long hi = __hip_atomic_load(aq + (size_t)j * 128 + 1,
                                      __ATOMIC_RELAXED, __HIP_MEMORY_SCOPE_AGENT);
            av[4 * j + 0] = __uint_as_float((unsigned)(lo & 0xffffffffu));
            av[4 * j + 1] = __uint_as_float((unsigned)(lo >> 32));
            av[4 * j + 2] = __uint_as_float((unsigned)(hi & 0xffffffffu));
            av[4 * j + 3] = __uint_as_float((unsigned)(hi >> 32));
        }

        // W from the staged LDS buffer, wave-uniform broadcast reads
        const float* wl = wstg[cur] + s * 64;
        float acc[8];
#pragma unroll
        for (int col = 0; col < 8; ++col) {
            const float* wp = wl + col * 1024;
            float sum = 0.f;
#pragma unroll
            for (int k = 0; k < 64; ++k)
                sum = fmaf(wp[k], av[k], sum);
            acc[col] = sum;
        }

        // ---- one-pass gate reduce + epilogue (R5 verbatim) ----
        redA[s][b] = make_float4(acc[0], acc[1], acc[2], acc[3]);
        redB[s][b] = make_float4(acc[4], acc[5], acc[6], acc[7]);
        __syncthreads();

        if (tid < 128) {
            const int hn = tid >> 6;
            const float4* plane = hn ? &redB[0][0] : &redA[0][0];
            int b2 = tid & 63;
            float gx = 0.f, gy = 0.f, gz = 0.f, gw = 0.f;
#pragma unroll
            for (int ss = 0; ss < 16; ++ss) {
                float4 r = plane[ss * 64 + b2];
                gx += r.x; gy += r.y; gz += r.z; gw += r.w;
            }
            float4 bb4 = *(const float4*)(biasC + l * G4 + bid * 8 + hn * 4);
            float ig = sigmoidf_(gx + bb4.x);
            float fg = sigmoidf_(gy + bb4.y);
            float gv = tanhf(gz + bb4.z);
            float og = sigmoidf_(gw + bb4.w);

            float cn = fg * cst[l][hn][b2] + ig * gv;
            cst[l][hn][b2] = cn;
            float hv = og * tanhf(cn);

            int n = bid * 2 + hn;
            __hip_atomic_store(
                &hT[(size_t)(par * 4 + l) * 32768 + ((n >> 2) * 64 + b2) * 4 + (n & 3)],
                hv, __ATOMIC_RELAXED, __HIP_MEMORY_SCOPE_AGENT);
            if (l == Lv - 1)
                out[((size_t)b2 * Tv + t) * Hv + n] = hv;
        }
        __syncthreads();

        // ---- inter-block barrier (monotonic, spread counters, R5 verbatim)
        if (tid == 0)
            __hip_atomic_fetch_add(&bar8[(bid & 7) * 16], 1,
                                   __ATOMIC_RELEASE, __HIP_MEMORY_SCOPE_AGENT);
        if (tid < 8) {
            const int target = 32 * (p + 1);
            while (__hip_atomic_load(&bar8[tid * 16], __ATOMIC_RELAXED,
                                     __HIP_MEMORY_SCOPE_AGENT) < target) {}
        }
        __syncthreads();
    }
    #undef STAGE
}

extern "C" void kernel_launch(void* const* d_in, const int* in_sizes, int n_in,
                              void* d_out, int out_size, void* d_ws, size_t ws_size,
                              hipStream_t stream)
{
    const float* y   = (const float*)d_in[0];
    const float* h0  = (const float*)d_in[1];
    const float* c0  = (const float*)d_in[2];
    const float* Wih = (const float*)d_in[3];
    const float* Whh = (const float*)d_in[4];
    const float* bih = (const float*)d_in[5];
    const float* bhh = (const float*)d_in[6];
    float* out = (float*)d_out;

    char* ws = (char*)d_ws;
    float* wt    = (float*)(ws + WT_OFF);
    float* hT    = (float*)(ws + HT_OFF);
    float* yT    = (float*)(ws + YT_OFF);
    float* biasC = (float*)(ws + BIAS_OFF);
    int*   bar8  = (int*)(ws + BAR_OFF);

    hipMemsetAsync(ws + BAR_OFF, 0, 1024, stream);

    prep_wt<<<NBLK, 256, 0, stream>>>(Wih, Whh, wt);
    prep_bias<<<32, 256, 0, stream>>>(bih, bhh, biasC);
    prep_act<<<(32768 + 131072) / 256, 256, 0, stream>>>(y, h0, yT, hT);

    lstm_persist<<<NBLK, NTHR, 0, stream>>>(wt, biasC, yT, c0, hT, out, bar8);
}